// Round 3
// baseline (365.113 us; speedup 1.0000x reference)
//
#include <hip/hip_runtime.h>
#include <hip/hip_bf16.h>

#define D_DIM 768
#define B_DIM 8192
#define NCHUNK 8    // column chunks (grid.y)
#define CT 8        // col-tiles of 128 per chunk
#define BM 128
#define BN 128
#define BK 64
#define CAP 32      // survivor buffer slots per row per tile

typedef __attribute__((ext_vector_type(8))) short short8;
typedef __attribute__((ext_vector_type(4))) float f32x4;
typedef __attribute__((ext_vector_type(4))) unsigned short ushort4v;

// ws layout (bytes)
#define WS_XB   0                               // bf16[8192*768] = 12,582,912
#define WS_SQ   12582912                        // float[8192]    = 32,768
#define WS_CAND 12615680                        // float[8192*8*8] = 2,097,152
#define WS_ACC  14712832                        // float acc + int completion counter

__device__ __forceinline__ void gl_lds16(const void* g, void* lds) {
  __builtin_amdgcn_global_load_lds(
      (const __attribute__((address_space(1))) unsigned int*)g,
      (__attribute__((address_space(3))) unsigned int*)lds, 16, 0, 0);
}

// maintain v[0..5] = six smallest seen, sorted ascending (v[5] = max)
__device__ __forceinline__ void ins6(float c, float* v) {
  if (c < v[5]) {
    v[5] = c;
#pragma unroll
    for (int s = 5; s > 0; --s) {
      float lo = fminf(v[s - 1], v[s]);
      float hi = fmaxf(v[s - 1], v[s]);
      v[s - 1] = lo;
      v[s] = hi;
    }
  }
}

// kernel 1: cast fp32 -> bf16 (vectorized), row sum-of-squares of bf16 values.
__global__ __launch_bounds__(256) void cast_sq_kernel(
    const float* __restrict__ x, unsigned short* __restrict__ xb,
    float* __restrict__ sq, float* __restrict__ accw) {
  const int t = threadIdx.x;
  const int w = t >> 6, lane = t & 63;
  const int row = blockIdx.x * 4 + w;
  if (blockIdx.x == 0 && t == 0) { accw[0] = 0.0f; ((int*)accw)[1] = 0; }
  const f32x4* xr = (const f32x4*)(x + (size_t)row * D_DIM);
  ushort4v* xbr = (ushort4v*)(xb + (size_t)row * D_DIM);
  float s = 0.0f;
#pragma unroll
  for (int c = 0; c < 3; ++c) {
    const int idx = c * 64 + lane;
    f32x4 v = xr[idx];
    ushort4v u;
#pragma unroll
    for (int e = 0; e < 4; ++e) {
      __hip_bfloat16 h = __float2bfloat16(v[e]);
      unsigned short us;
      __builtin_memcpy(&us, &h, 2);
      u[e] = us;
      float vb = __bfloat162float(h);
      s += vb * vb;
    }
    xbr[idx] = u;
  }
#pragma unroll
  for (int off = 32; off > 0; off >>= 1) s += __shfl_down(s, off, 64);
  if (lane == 0) sq[row] = s;
}

// kernel 2: fused bf16 MFMA Gram-tile + threshold-gated top-6 selection.
__global__ __launch_bounds__(256) void knn_gemm_kernel(
    const unsigned short* __restrict__ xb, const float* __restrict__ sq,
    float* __restrict__ cand) {
  __shared__ __align__(16) char smem[40960];
  unsigned short* As = (unsigned short*)smem;          // staging [128][64] bf16
  unsigned short* Bs = (unsigned short*)(smem + 16384);
  // slow-path (ct==0) buffers, alias staging region (used post-K-loop only):
  float* distS = (float*)smem;                         // [64][132] f32
  float* candS = (float*)(smem + 33792);               // [64][24]
  // fast-path (ct>=1) buffers, alias staging region (used post-K-loop only):
  float* thrS = (float*)smem;                          // [128]
  int* cntS = (int*)(smem + 512);                      // [128]
  int* flagS = (int*)(smem + 1024);                    // [1]
  float* candbufS = (float*)(smem + 1040);             // [128][CAP] = 16384 B
  float* fbS = (float*)(smem + 17440);                 // [128] fallback row buffer

  const int t = threadIdx.x;
  const int lane = t & 63;
  const int w = t >> 6;
  const int wm = w >> 1, wn = w & 1;                   // 2x2 wave grid, 64x64 each
  const int quad = lane >> 4, m16 = lane & 15;

  const int rowBase = blockIdx.x * BM;
  const int chunk = blockIdx.y;

  // staging swizzle: LDS slot (row r, seg s) holds global seg s^(r&7)
  int srcOff[4], ldsOff[4];
#pragma unroll
  for (int q = 0; q < 4; ++q) {
    const int e = q * 2048 + t * 8;
    const int r = e >> 6;
    const int seg = (e >> 3) & 7;
    srcOff[q] = r * D_DIM + (seg ^ (r & 7)) * 8;
    ldsOff[q] = e * 2;
  }

  float rsq[16];
#pragma unroll
  for (int i = 0; i < 4; ++i)
#pragma unroll
    for (int r = 0; r < 4; ++r)
      rsq[i * 4 + r] = sq[rowBase + wm * 64 + i * 16 + quad * 4 + r];

  float run[6];
#pragma unroll
  for (int s = 0; s < 6; ++s) run[s] = 1e30f;

  for (int ct = 0; ct < CT; ++ct) {
    const int colBase = chunk * (CT * BN) + ct * BN;
    float csq[4];
#pragma unroll
    for (int j = 0; j < 4; ++j)
      csq[j] = sq[colBase + wn * 64 + j * 16 + m16];

    f32x4 acc[4][4];
    const f32x4 zero = {0.0f, 0.0f, 0.0f, 0.0f};
#pragma unroll
    for (int i = 0; i < 4; ++i)
#pragma unroll
      for (int j = 0; j < 4; ++j) acc[i][j] = zero;

    for (int kt = 0; kt < D_DIM / BK; ++kt) {
      const int k0 = kt * BK;
      __syncthreads();
#pragma unroll
      for (int q = 0; q < 4; ++q) {
        gl_lds16(xb + (size_t)rowBase * D_DIM + k0 + srcOff[q], (char*)As + ldsOff[q]);
        gl_lds16(xb + (size_t)colBase * D_DIM + k0 + srcOff[q], (char*)Bs + ldsOff[q]);
      }
      __syncthreads();
#pragma unroll
      for (int kk = 0; kk < 2; ++kk) {
        short8 a[4], b[4];
#pragma unroll
        for (int i = 0; i < 4; ++i) {
          const int R = wm * 64 + i * 16 + m16;
          const int s = (kk * 4 + quad) ^ (R & 7);
          a[i] = *(const short8*)(As + R * 64 + s * 8);
        }
#pragma unroll
        for (int j = 0; j < 4; ++j) {
          const int R = wn * 64 + j * 16 + m16;
          const int s = (kk * 4 + quad) ^ (R & 7);
          b[j] = *(const short8*)(Bs + R * 64 + s * 8);
        }
#pragma unroll
        for (int i = 0; i < 4; ++i)
#pragma unroll
          for (int j = 0; j < 4; ++j)
            acc[i][j] = __builtin_amdgcn_mfma_f32_16x16x32_bf16(a[i], b[j], acc[i][j], 0, 0, 0);
      }
    }

    if (ct == 0) {
      // ---- slow epilogue: bootstrap run[] from the first 128 cols ----
      for (int h = 0; h < 2; ++h) {
        __syncthreads();
        if (wm == h) {
          // C layout: col = lane&15, row = quad*4 + reg  [verified m89/m91]
#pragma unroll
          for (int i = 0; i < 4; ++i)
#pragma unroll
            for (int j = 0; j < 4; ++j)
#pragma unroll
              for (int r = 0; r < 4; ++r) {
                const int row_l = i * 16 + quad * 4 + r;
                const int col = wn * 64 + j * 16 + m16;
                distS[row_l * 132 + col] = rsq[i * 4 + r] + csq[j] - 2.0f * acc[i][j][r];
              }
        }
        __syncthreads();
        {
          const int row_l = t >> 2, seg = t & 3;
          const f32x4* dr4 = (const f32x4*)(distS + row_l * 132 + seg * 32);
          float v[6];
#pragma unroll
          for (int s = 0; s < 6; ++s) v[s] = 1e30f;
#pragma unroll
          for (int c4 = 0; c4 < 8; ++c4) {
            f32x4 dv = dr4[c4];
            ins6(dv[0], v); ins6(dv[1], v); ins6(dv[2], v); ins6(dv[3], v);
          }
#pragma unroll
          for (int s = 0; s < 6; ++s) candS[row_l * 24 + seg * 6 + s] = v[s];
        }
        __syncthreads();
        if ((t >> 6) == h) {
          const int row_l = t - h * 64;
#pragma unroll
          for (int c = 0; c < 24; ++c) ins6(candS[row_l * 24 + c], run);
        }
      }
    } else {
      // ---- fast epilogue: threshold-gated survivor collection ----
      __syncthreads();  // staging reads done; safe to overwrite aliased bufs
      if (t < BM) { thrS[t] = run[5]; cntS[t] = 0; }
      if (t == 0) *flagS = 0;
      __syncthreads();
      float thrp[16];
#pragma unroll
      for (int i = 0; i < 4; ++i)
#pragma unroll
        for (int r = 0; r < 4; ++r) {
          const int row = wm * 64 + i * 16 + quad * 4 + r;
          thrp[i * 4 + r] = thrS[row] - rsq[i * 4 + r];
        }
#pragma unroll
      for (int i = 0; i < 4; ++i)
#pragma unroll
        for (int j = 0; j < 4; ++j)
#pragma unroll
          for (int r = 0; r < 4; ++r) {
            const float s = fmaf(-2.0f, acc[i][j][r], csq[j]);
            if (s < thrp[i * 4 + r]) {
              const int row = wm * 64 + i * 16 + quad * 4 + r;
              const int slot = atomicAdd(&cntS[row], 1);
              if (slot < CAP) candbufS[row * CAP + slot] = s + rsq[i * 4 + r];
            }
          }
      __syncthreads();
      if (t < BM) {
        const int n = cntS[t];
        if (n <= CAP) {
          for (int c = 0; c < n; ++c) ins6(candbufS[t * CAP + c], run);
        } else {
          *flagS = 1;  // benign race, same value
        }
      }
      __syncthreads();
      if (*flagS) {
        // exact fallback: rescan overflowed rows over this tile's 128 cols.
        // (owners of such rows did NOT merge candbuf — no double counting)
        for (int r = 0; r < BM; ++r) {
          if (cntS[r] <= CAP) continue;  // uniform branch
          const int r6 = r & 63;
          const int iN = r6 >> 4, qN = (r6 >> 2) & 3, rN = r6 & 3;
#pragma unroll
          for (int i = 0; i < 4; ++i)
#pragma unroll
            for (int rr = 0; rr < 4; ++rr)
              if (i == iN && rr == rN && quad == qN && wm == (r >> 6)) {
#pragma unroll
                for (int j = 0; j < 4; ++j)
                  fbS[wn * 64 + j * 16 + m16] =
                      rsq[i * 4 + rr] + fmaf(-2.0f, acc[i][j][rr], csq[j]);
              }
          __syncthreads();
          if (t == r) {
            for (int c = 0; c < BN; ++c) ins6(fbS[c], run);
          }
          __syncthreads();
        }
      }
    }
  }

  if (t < BM) {
    float* o = cand + ((size_t)(rowBase + t) * NCHUNK + chunk) * 8;
#pragma unroll
    for (int s = 0; s < 6; ++s) o[s] = run[s];
  }
}

// kernel 3: per-row merge of chunk candidates (d^2) -> sqrt -> log -> sum -> finalize
__global__ __launch_bounds__(256) void knn_merge_kernel(
    const float* __restrict__ cand, float* __restrict__ accw,
    float* __restrict__ out) {
  const int r = blockIdx.x * 256 + threadIdx.x;
  const float* cr = cand + (size_t)r * (NCHUNK * 8);
  float v[6];
#pragma unroll
  for (int s = 0; s < 6; ++s) v[s] = 1e30f;
  for (int c = 0; c < NCHUNK; ++c) {
#pragma unroll
    for (int s = 0; s < 6; ++s) ins6(cr[c * 8 + s], v);
  }
  // v sorted ascending on d^2: v[0] = self; knn_mean = mean of sqrt(v[1..5])
  const float mean = (sqrtf(fmaxf(v[1], 0.0f)) + sqrtf(fmaxf(v[2], 0.0f)) +
                      sqrtf(fmaxf(v[3], 0.0f)) + sqrtf(fmaxf(v[4], 0.0f)) +
                      sqrtf(fmaxf(v[5], 0.0f))) * 0.2f;
  float term = logf(mean + 1e-8f);
#pragma unroll
  for (int off = 32; off > 0; off >>= 1) term += __shfl_down(term, off, 64);
  __shared__ float red[4];
  if ((threadIdx.x & 63) == 0) red[threadIdx.x >> 6] = term;
  __syncthreads();
  if (threadIdx.x == 0) {
    atomicAdd(accw, red[0] + red[1] + red[2] + red[3]);
    __threadfence();
    const int old = atomicAdd((int*)accw + 1, 1);
    if (old == (int)gridDim.x - 1) {
      __threadfence();
      const float tot = atomicAdd(accw, 0.0f);  // all adds visible
      out[0] = -tot * (1.0f / 8192.0f);
    }
  }
}

extern "C" void kernel_launch(void* const* d_in, const int* in_sizes, int n_in,
                              void* d_out, int out_size, void* d_ws, size_t ws_size,
                              hipStream_t stream) {
  const float* x = (const float*)d_in[0];
  float* out = (float*)d_out;
  char* ws = (char*)d_ws;
  unsigned short* xb = (unsigned short*)(ws + WS_XB);
  float* sq = (float*)(ws + WS_SQ);
  float* cand = (float*)(ws + WS_CAND);
  float* accw = (float*)(ws + WS_ACC);

  cast_sq_kernel<<<B_DIM / 4, 256, 0, stream>>>(x, xb, sq, accw);
  knn_gemm_kernel<<<dim3(B_DIM / BM, NCHUNK), 256, 0, stream>>>(xb, sq, cand);
  knn_merge_kernel<<<B_DIM / 256, 256, 0, stream>>>(cand, accw, out);
}